// Round 1
// baseline (2472.178 us; speedup 1.0000x reference)
//
#include <hip/hip_runtime.h>
#include <math.h>

// ---------------------------------------------------------------------------
// VDPWI forward, full fp32 baseline.
// B=256, L=32, D=300, H=250, NLAB=5. NEG=-10000.
// Workspace peak ~138 MB (conv buffers reuse the dead sT/xW region).
// ---------------------------------------------------------------------------

#define NEGV (-10000.0f)

__device__ __forceinline__ float4 load4g(const float* __restrict__ p, int k, int K) {
  float4 r;
  if (k + 3 < K) {
    r = *(const float4*)(p + k);
  } else {
    r.x = (k     < K) ? p[k]     : 0.f;
    r.y = (k + 1 < K) ? p[k + 1] : 0.f;
    r.z = (k + 2 < K) ? p[k + 2] : 0.f;
    r.w = (k + 3 < K) ? p[k + 3] : 0.f;
  }
  return r;
}

// ---------------- zero init (h0 = c0 = 0) ----------------
__global__ __launch_bounds__(256) void zero_kernel(float* p, int n) {
  int i = blockIdx.x * 256 + threadIdx.x;
  if (i < n) p[i] = 0.f;
}

// ---------------- transpose sent [B,D,L] -> sT [2,B,L,D] ----------------
__global__ __launch_bounds__(256) void transpose_sent(const float* __restrict__ sent1,
                                                      const float* __restrict__ sent2,
                                                      float* __restrict__ sT) {
  int blk = blockIdx.x;            // s*256 + b
  int s = blk >> 8, b = blk & 255;
  const float* in = (s ? sent2 : sent1) + (size_t)b * 9600;   // [300][32]
  float* out = sT + (size_t)blk * 9600;                        // [32][300]
  __shared__ float lds[300 * 33];
  for (int idx = threadIdx.x; idx < 9600; idx += 256) {
    int d = idx >> 5, tt = idx & 31;
    lds[d * 33 + tt] = in[idx];
  }
  __syncthreads();
  for (int odx = threadIdx.x; odx < 9600; odx += 256) {
    int tt = odx / 300, d = odx % 300;
    out[odx] = lds[d * 33 + tt];
  }
}

// ---------------- xW GEMM: xW[s,t,b,j] = sT[s,b,t,:]·Wih[j,:] + bih[j]+bhh[j]
// M=16384 (i = s*8192 + t*256 + b), N=1000, K=300. BM=BN=64, BK=16, 4x4/thread.
__global__ __launch_bounds__(256) void gemm_xw(const float* __restrict__ sT,
                                               const float* __restrict__ Wih,
                                               const float* __restrict__ bih,
                                               const float* __restrict__ bhh,
                                               float* __restrict__ xW) {
  __shared__ float As[16][68];
  __shared__ float Bs[16][68];
  const int tid = threadIdx.x;
  const int i0 = blockIdx.x * 64;
  const int j0 = blockIdx.y * 64;
  const int tx = tid & 15, ty = tid >> 4;
  const int sm = tid >> 2, skq = (tid & 3) * 4;

  int i = i0 + sm;
  int s = i >> 13, r = i & 8191, t = r >> 8, bb = r & 255;
  const float* arow = sT + (size_t)(((s << 8) + bb) * 32 + t) * 300;
  int jrow = j0 + sm;
  bool jv = jrow < 1000;
  const float* wrow = Wih + (size_t)(jv ? jrow : 0) * 300;

  float acc[4][4];
#pragma unroll
  for (int a = 0; a < 4; a++)
#pragma unroll
    for (int c = 0; c < 4; c++) acc[a][c] = 0.f;

  for (int k0 = 0; k0 < 300; k0 += 16) {
    float4 av = load4g(arow, k0 + skq, 300);
    float4 wv;
    if (jv) wv = load4g(wrow, k0 + skq, 300);
    else { wv.x = wv.y = wv.z = wv.w = 0.f; }
    __syncthreads();
    As[skq + 0][sm] = av.x; As[skq + 1][sm] = av.y; As[skq + 2][sm] = av.z; As[skq + 3][sm] = av.w;
    Bs[skq + 0][sm] = wv.x; Bs[skq + 1][sm] = wv.y; Bs[skq + 2][sm] = wv.z; Bs[skq + 3][sm] = wv.w;
    __syncthreads();
#pragma unroll
    for (int k = 0; k < 16; k++) {
      float4 a = *(const float4*)&As[k][ty * 4];
      float4 bvec = *(const float4*)&Bs[k][tx * 4];
      acc[0][0] = fmaf(a.x, bvec.x, acc[0][0]); acc[0][1] = fmaf(a.x, bvec.y, acc[0][1]);
      acc[0][2] = fmaf(a.x, bvec.z, acc[0][2]); acc[0][3] = fmaf(a.x, bvec.w, acc[0][3]);
      acc[1][0] = fmaf(a.y, bvec.x, acc[1][0]); acc[1][1] = fmaf(a.y, bvec.y, acc[1][1]);
      acc[1][2] = fmaf(a.y, bvec.z, acc[1][2]); acc[1][3] = fmaf(a.y, bvec.w, acc[1][3]);
      acc[2][0] = fmaf(a.z, bvec.x, acc[2][0]); acc[2][1] = fmaf(a.z, bvec.y, acc[2][1]);
      acc[2][2] = fmaf(a.z, bvec.z, acc[2][2]); acc[2][3] = fmaf(a.z, bvec.w, acc[2][3]);
      acc[3][0] = fmaf(a.w, bvec.x, acc[3][0]); acc[3][1] = fmaf(a.w, bvec.y, acc[3][1]);
      acc[3][2] = fmaf(a.w, bvec.z, acc[3][2]); acc[3][3] = fmaf(a.w, bvec.w, acc[3][3]);
    }
  }
  int jb = j0 + tx * 4;
  if (jb < 1000) {
    float b0 = bih[jb]     + bhh[jb];
    float b1 = bih[jb + 1] + bhh[jb + 1];
    float b2 = bih[jb + 2] + bhh[jb + 2];
    float b3 = bih[jb + 3] + bhh[jb + 3];
#pragma unroll
    for (int rr = 0; rr < 4; rr++) {
      int irow = i0 + ty * 4 + rr;
      float4 o;
      o.x = acc[rr][0] + b0; o.y = acc[rr][1] + b1; o.z = acc[rr][2] + b2; o.w = acc[rr][3] + b3;
      *(float4*)(xW + (size_t)irow * 1000 + jb) = o;
    }
  }
}

// ---------------- recurrence GEMM: g[i,j] = h[i,:]·Whh[j,:] + xW[s,tin,b,j]
// M=1024 (i = l*256+b; l: 0=s1f,1=s1b,2=s2f,3=s2b), N=1000, K=250.
__global__ __launch_bounds__(256) void gemm_rec(const float* __restrict__ hbuf,
                                                const float* __restrict__ Whh,
                                                const float* __restrict__ xW,
                                                float* __restrict__ gbuf, int t) {
  __shared__ float As[16][68];
  __shared__ float Bs[16][68];
  const int tid = threadIdx.x;
  const int i0 = blockIdx.x * 64;
  const int j0 = blockIdx.y * 64;
  const int tx = tid & 15, ty = tid >> 4;
  const int sm = tid >> 2, skq = (tid & 3) * 4;

  const float* arow = hbuf + (size_t)(i0 + sm) * 250;
  int jrow = j0 + sm;
  bool jv = jrow < 1000;
  const float* wrow = Whh + (size_t)(jv ? jrow : 0) * 250;

  float acc[4][4];
#pragma unroll
  for (int a = 0; a < 4; a++)
#pragma unroll
    for (int c = 0; c < 4; c++) acc[a][c] = 0.f;

  for (int k0 = 0; k0 < 250; k0 += 16) {
    float4 av = load4g(arow, k0 + skq, 250);
    float4 wv;
    if (jv) wv = load4g(wrow, k0 + skq, 250);
    else { wv.x = wv.y = wv.z = wv.w = 0.f; }
    __syncthreads();
    As[skq + 0][sm] = av.x; As[skq + 1][sm] = av.y; As[skq + 2][sm] = av.z; As[skq + 3][sm] = av.w;
    Bs[skq + 0][sm] = wv.x; Bs[skq + 1][sm] = wv.y; Bs[skq + 2][sm] = wv.z; Bs[skq + 3][sm] = wv.w;
    __syncthreads();
#pragma unroll
    for (int k = 0; k < 16; k++) {
      float4 a = *(const float4*)&As[k][ty * 4];
      float4 bvec = *(const float4*)&Bs[k][tx * 4];
      acc[0][0] = fmaf(a.x, bvec.x, acc[0][0]); acc[0][1] = fmaf(a.x, bvec.y, acc[0][1]);
      acc[0][2] = fmaf(a.x, bvec.z, acc[0][2]); acc[0][3] = fmaf(a.x, bvec.w, acc[0][3]);
      acc[1][0] = fmaf(a.y, bvec.x, acc[1][0]); acc[1][1] = fmaf(a.y, bvec.y, acc[1][1]);
      acc[1][2] = fmaf(a.y, bvec.z, acc[1][2]); acc[1][3] = fmaf(a.y, bvec.w, acc[1][3]);
      acc[2][0] = fmaf(a.z, bvec.x, acc[2][0]); acc[2][1] = fmaf(a.z, bvec.y, acc[2][1]);
      acc[2][2] = fmaf(a.z, bvec.z, acc[2][2]); acc[2][3] = fmaf(a.z, bvec.w, acc[2][3]);
      acc[3][0] = fmaf(a.w, bvec.x, acc[3][0]); acc[3][1] = fmaf(a.w, bvec.y, acc[3][1]);
      acc[3][2] = fmaf(a.w, bvec.z, acc[3][2]); acc[3][3] = fmaf(a.w, bvec.w, acc[3][3]);
    }
  }
  int jb = j0 + tx * 4;
  if (jb < 1000) {
#pragma unroll
    for (int rr = 0; rr < 4; rr++) {
      int irow = i0 + ty * 4 + rr;
      int l = irow >> 8, b = irow & 255;
      int s = l >> 1, dir = l & 1;
      int tin = dir ? (31 - t) : t;
      const float* xp = xW + (size_t)(((s * 32 + tin) << 8) + b) * 1000;
      float4 xv = *(const float4*)(xp + jb);
      float4 o;
      o.x = acc[rr][0] + xv.x; o.y = acc[rr][1] + xv.y;
      o.z = acc[rr][2] + xv.z; o.w = acc[rr][3] + xv.w;
      *(float4*)(gbuf + (size_t)irow * 1000 + jb) = o;
    }
  }
}

// ---------------- LSTM gates (torch order i,f,g,o) ----------------
__global__ __launch_bounds__(256) void lstm_gates(const float* __restrict__ gbuf,
                                                  float* __restrict__ hbuf,
                                                  float* __restrict__ cbuf,
                                                  float* __restrict__ seq, int t) {
  int idx = blockIdx.x * 256 + threadIdx.x;     // < 4*256*250
  int u = idx % 250;
  int ib = idx / 250;                            // l*256 + b
  const float* g = gbuf + (size_t)ib * 1000;
  float gi = g[u], gf = g[250 + u], gg = g[500 + u], go = g[750 + u];
  float c = cbuf[idx];
  float si = 1.f / (1.f + expf(-gi));
  float sf = 1.f / (1.f + expf(-gf));
  float so = 1.f / (1.f + expf(-go));
  float tg = tanhf(gg);
  float cn = sf * c + si * tg;
  float h = so * tanhf(cn);
  cbuf[idx] = cn;
  hbuf[idx] = h;
  seq[(size_t)(ib * 32 + t) * 250 + u] = h;
}

// ---------------- similarities: 12 channels + NEG padding ----------------
// seq: [4][256][32][250] (0=s1f,1=s1b,2=s2f,3=s2b). simm: [B][12][32][32].
__global__ __launch_bounds__(256) void sim_kernel(const float* __restrict__ seq,
                                                  const int* __restrict__ len1,
                                                  const int* __restrict__ len2,
                                                  float* __restrict__ simm) {
  __shared__ float lds[4][32][65];
  const int b = blockIdx.x, tid = threadIdx.x;
  float dff[4], dbb[4], d9[4];
  float nf1[4], nb1[4], n91[4], nf2[4], nb2[4], n92[4];
#pragma unroll
  for (int pp = 0; pp < 4; pp++) {
    dff[pp] = dbb[pp] = d9[pp] = 0.f;
    nf1[pp] = nb1[pp] = n91[pp] = nf2[pp] = nb2[pp] = n92[pp] = 0.f;
  }
  for (int k0 = 0; k0 < 250; k0 += 64) {
    __syncthreads();
    for (int idx = tid; idx < 4 * 32 * 64; idx += 256) {
      int mat = idx >> 11, row = (idx >> 6) & 31, kk = idx & 63;
      int k = k0 + kk;
      lds[mat][row][kk] = (k < 250) ? seq[(size_t)((mat * 256 + b) * 32 + row) * 250 + k] : 0.f;
    }
    __syncthreads();
#pragma unroll
    for (int pp = 0; pp < 4; pp++) {
      int pr = tid + (pp << 8);
      int l = pr >> 5, m = pr & 31;
      for (int kk = 0; kk < 64; kk++) {
        float af = lds[0][l][kk], ab = lds[1][l][kk];
        float bf = lds[2][m][kk], bbv = lds[3][m][kk];
        float s1 = af + ab, s2 = bf + bbv;
        dff[pp] = fmaf(af, bf, dff[pp]);
        dbb[pp] = fmaf(ab, bbv, dbb[pp]);
        d9[pp]  = fmaf(s1, s2, d9[pp]);
        nf1[pp] = fmaf(af, af, nf1[pp]);
        nb1[pp] = fmaf(ab, ab, nb1[pp]);
        n91[pp] = fmaf(s1, s1, n91[pp]);
        nf2[pp] = fmaf(bf, bf, nf2[pp]);
        nb2[pp] = fmaf(bbv, bbv, nb2[pp]);
        n92[pp] = fmaf(s2, s2, n92[pp]);
      }
    }
  }
  int L1 = len1[b], L2 = len2[b];
  float* sb = simm + (size_t)b * 12 * 1024;
#pragma unroll
  for (int pp = 0; pp < 4; pp++) {
    int pr = tid + (pp << 8);
    int l = pr >> 5, m = pr & 31;
    float padv = (l >= L1 || m >= L2) ? NEGV : 0.f;
    float dcat = dff[pp] + dbb[pp];
    float n1c = nf1[pp] + nb1[pp], n2c = nf2[pp] + nb2[pp];
    sb[0 * 1024 + pr] = dcat + padv;
    sb[1 * 1024 + pr] = dcat / (sqrtf(n1c) * sqrtf(n2c) + 1e-8f) + padv;
    sb[2 * 1024 + pr] = sqrtf(fmaxf(n1c + n2c - 2.f * dcat, 1e-12f)) + padv;
    sb[3 * 1024 + pr] = dff[pp] + padv;
    sb[4 * 1024 + pr] = dff[pp] / (sqrtf(nf1[pp]) * sqrtf(nf2[pp]) + 1e-8f) + padv;
    sb[5 * 1024 + pr] = sqrtf(fmaxf(nf1[pp] + nf2[pp] - 2.f * dff[pp], 1e-12f)) + padv;
    sb[6 * 1024 + pr] = dbb[pp] + padv;
    sb[7 * 1024 + pr] = dbb[pp] / (sqrtf(nb1[pp]) * sqrtf(nb2[pp]) + 1e-8f) + padv;
    sb[8 * 1024 + pr] = sqrtf(fmaxf(nb1[pp] + nb2[pp] - 2.f * dbb[pp], 1e-12f)) + padv;
    sb[9 * 1024 + pr] = d9[pp] + padv;
    sb[10 * 1024 + pr] = d9[pp] / (sqrtf(n91[pp]) * sqrtf(n92[pp]) + 1e-8f) + padv;
    sb[11 * 1024 + pr] = sqrtf(fmaxf(n91[pp] + n92[pp] - 2.f * d9[pp], 1e-12f)) + padv;
  }
}

// ---------------- greedy NMS-style select on ch9 | ch10 -> mask (1.0/0.1) ----
// One wave per image. Values fully register-resident (16 per lane, idx = lane + 64q).
__global__ __launch_bounds__(64) void greedy_kernel(const float* __restrict__ simm,
                                                    float* __restrict__ maskf) {
  const int b = blockIdx.x, lane = threadIdx.x;
  unsigned sel = 0;
#pragma unroll 1
  for (int ch = 0; ch < 2; ch++) {
    const float* mm = simm + (size_t)(b * 12 + 9 + ch) * 1024;
    float v[16];
#pragma unroll
    for (int q = 0; q < 16; q++) v[q] = mm[lane + (q << 6)];
#pragma unroll 1
    for (int it = 0; it < 32; it++) {
      float bv = v[0]; int bi = lane;
#pragma unroll
      for (int q = 1; q < 16; q++) {
        int idx = lane + (q << 6);
        if (v[q] > bv) { bv = v[q]; bi = idx; }
      }
#pragma unroll
      for (int off = 32; off > 0; off >>= 1) {
        float ov = __shfl_xor(bv, off);
        int oi = __shfl_xor(bi, off);
        if (ov > bv || (ov == bv && oi < bi)) { bv = ov; bi = oi; }
      }
      if (bv < -5000.0f) break;          // val >= NEG/2 is "active"
      int rr = bi >> 5, cc = bi & 31;
#pragma unroll
      for (int q = 0; q < 16; q++) {
        int idx = lane + (q << 6);
        int ri = idx >> 5, ci = idx & 31;
        if (idx == bi) sel |= (1u << q);
        if (ri == rr || ci == cc) v[q] = NEGV;
      }
    }
  }
#pragma unroll
  for (int q = 0; q < 16; q++)
    maskf[(size_t)b * 1024 + lane + (q << 6)] = ((sel >> q) & 1u) ? 1.0f : 0.1f;
}

// ---------------- focus = mask * simm * (1 - pad), in place ----------------
__global__ __launch_bounds__(256) void focus_kernel(float* __restrict__ simm,
                                                    const float* __restrict__ maskf,
                                                    const int* __restrict__ len1,
                                                    const int* __restrict__ len2) {
  int idx = blockIdx.x * 256 + threadIdx.x;     // < 256*12*1024
  int cell = idx & 1023;
  int bc = idx >> 10;
  int b = bc / 12;
  int l = cell >> 5, m = cell & 31;
  bool pad = (l >= len1[b]) || (m >= len2[b]);
  float v = simm[idx];
  simm[idx] = pad ? 0.f : v * maskf[((size_t)b << 10) + cell];
}

// ---------------- fused conv3x3(SAME) + bias + relu + maxpool2 ----------------
// One block per image. Input staged in LDS (ICC channel chunks). Threads:
// pooled pixel = tid%P, oc-slice = tid/P; OCB output channels register-blocked.
template<int CIN, int S, int OCB, int ICC>
__global__ __launch_bounds__(256) void conv_pool(const float* __restrict__ in,
                                                 const float* __restrict__ w,
                                                 const float* __restrict__ bias,
                                                 float* __restrict__ out, int COUT) {
  constexpr int SOUT = S / 2;
  constexpr int P = SOUT * SOUT;
  constexpr int NSL = 256 / P;
  __shared__ float lds[ICC * S * S];
  const int b = blockIdx.x;
  const int tid = threadIdx.x;
  const int p = tid % P;
  const int slice = tid / P;
  const int py = p / SOUT, px = p % SOUT;
  const int y0 = 2 * py, x0 = 2 * px;
  const int ngroups = (COUT + OCB - 1) / OCB;
  const int giters = (ngroups + NSL - 1) / NSL;
  const float* inb = in + (size_t)b * CIN * S * S;

  if constexpr (ICC == CIN) {
    for (int idx = tid; idx < ICC * S * S / 4; idx += 256)
      ((float4*)lds)[idx] = ((const float4*)inb)[idx];
    __syncthreads();
  }

  for (int gi = 0; gi < giters; gi++) {
    int g = slice + gi * NSL;
    bool active = g < ngroups;
    int oc0 = active ? g * OCB : 0;
    const float* wrow[OCB];
#pragma unroll
    for (int o = 0; o < OCB; o++) {
      int oc = oc0 + o; if (oc > COUT - 1) oc = COUT - 1;
      wrow[o] = w + (size_t)oc * CIN * 9;
    }
    float acc[OCB][4];
#pragma unroll
    for (int o = 0; o < OCB; o++) { acc[o][0] = 0.f; acc[o][1] = 0.f; acc[o][2] = 0.f; acc[o][3] = 0.f; }

    for (int c0 = 0; c0 < CIN; c0 += ICC) {
      if constexpr (ICC < CIN) {
        __syncthreads();
        for (int idx = tid; idx < ICC * S * S / 4; idx += 256)
          ((float4*)lds)[idx] = ((const float4*)(inb + (size_t)c0 * S * S))[idx];
        __syncthreads();
      }
#pragma unroll 1
      for (int ic = 0; ic < ICC; ic++) {
        const float* base = lds + ic * S * S;
#pragma unroll
        for (int ky = 0; ky < 3; ky++) {
          int iy0 = y0 + ky - 1;
          int iy1 = y0 + ky;
          bool vy0 = (iy0 >= 0) && (iy0 < S);
          bool vy1 = (iy1 >= 0) && (iy1 < S);
#pragma unroll
          for (int kx = 0; kx < 3; kx++) {
            int ix0 = x0 + kx - 1;
            int ix1 = x0 + kx;
            bool vx0 = (ix0 >= 0) && (ix0 < S);
            bool vx1 = (ix1 >= 0) && (ix1 < S);
            float v00 = (vy0 && vx0) ? base[iy0 * S + ix0] : 0.f;
            float v01 = (vy0 && vx1) ? base[iy0 * S + ix1] : 0.f;
            float v10 = (vy1 && vx0) ? base[iy1 * S + ix0] : 0.f;
            float v11 = (vy1 && vx1) ? base[iy1 * S + ix1] : 0.f;
            int woff = (c0 + ic) * 9 + ky * 3 + kx;
#pragma unroll
            for (int o = 0; o < OCB; o++) {
              float wv = wrow[o][woff];
              acc[o][0] = fmaf(wv, v00, acc[o][0]);
              acc[o][1] = fmaf(wv, v01, acc[o][1]);
              acc[o][2] = fmaf(wv, v10, acc[o][2]);
              acc[o][3] = fmaf(wv, v11, acc[o][3]);
            }
          }
        }
      }
    }
    if (active) {
#pragma unroll
      for (int o = 0; o < OCB; o++) {
        int oc = oc0 + o;
        if (oc < COUT) {
          float m = fmaxf(fmaxf(acc[o][0], acc[o][1]), fmaxf(acc[o][2], acc[o][3]));
          out[((size_t)b * COUT + oc) * P + p] = fmaxf(m + bias[oc], 0.f);
        }
      }
    }
  }
}

// ---------------- dense(128->128, relu) + dense(128->5) + log_softmax ------
__global__ __launch_bounds__(128) void dense_head(const float* __restrict__ y5,
                                                  const float* __restrict__ dnn_w,
                                                  const float* __restrict__ dnn_b,
                                                  const float* __restrict__ out_w,
                                                  const float* __restrict__ out_b,
                                                  float* __restrict__ out) {
  __shared__ float xs[128];
  __shared__ float hs[128];
  __shared__ float lg[8];
  int b = blockIdx.x, j = threadIdx.x;
  xs[j] = y5[(size_t)b * 128 + j];
  __syncthreads();
  float acc = dnn_b[j];
  for (int k = 0; k < 128; k++) acc = fmaf(xs[k], dnn_w[j * 128 + k], acc);
  hs[j] = fmaxf(acc, 0.f);
  __syncthreads();
  if (j < 5) {
    float l = out_b[j];
    for (int k = 0; k < 128; k++) l = fmaf(hs[k], out_w[j * 128 + k], l);
    lg[j] = l;
  }
  __syncthreads();
  if (j < 5) {
    float m = lg[0];
    for (int c = 1; c < 5; c++) m = fmaxf(m, lg[c]);
    float ssum = 0.f;
    for (int c = 0; c < 5; c++) ssum += expf(lg[c] - m);
    out[(size_t)b * 5 + j] = lg[j] - m - logf(ssum);
  }
}

// ---------------------------------------------------------------------------
extern "C" void kernel_launch(void* const* d_in, const int* in_sizes, int n_in,
                              void* d_out, int out_size, void* d_ws, size_t ws_size,
                              hipStream_t stream) {
  (void)in_sizes; (void)n_in; (void)out_size; (void)ws_size;
  const float* sent1 = (const float*)d_in[0];
  const float* sent2 = (const float*)d_in[1];
  const int*   len1  = (const int*)d_in[2];
  const int*   len2  = (const int*)d_in[3];
  const float* Wih   = (const float*)d_in[4];
  const float* Whh   = (const float*)d_in[5];
  const float* bih   = (const float*)d_in[6];
  const float* bhh   = (const float*)d_in[7];
  const float* c1w = (const float*)d_in[8];  const float* c1b = (const float*)d_in[9];
  const float* c2w = (const float*)d_in[10]; const float* c2b = (const float*)d_in[11];
  const float* c3w = (const float*)d_in[12]; const float* c3b = (const float*)d_in[13];
  const float* c4w = (const float*)d_in[14]; const float* c4b = (const float*)d_in[15];
  const float* c5w = (const float*)d_in[16]; const float* c5b = (const float*)d_in[17];
  const float* dnn_w = (const float*)d_in[18]; const float* dnn_b = (const float*)d_in[19];
  const float* out_w = (const float*)d_in[20]; const float* out_b = (const float*)d_in[21];
  float* out = (float*)d_out;
  float* ws = (float*)d_ws;

  // -------- workspace layout (floats) --------
  float* sT    = ws;                 //  4,915,200  [2][256][32][300]
  float* xW    = ws + 4915200;       // 16,384,000  [2][32][256][1000]
  float* seq   = ws + 21299200;      //  8,192,000  [4][256][32][250]
  float* hbuf  = ws + 29491200;      //    256,000  [4][256][250]
  float* cbuf  = ws + 29747200;      //    256,000
  float* gbuf  = ws + 30003200;      //  1,024,000  [1024][1000]
  float* simm  = ws + 31027200;      //  3,145,728  [256][12][32][32]
  float* maskf = ws + 34172928;      //    262,144  [256][32][32]
  // conv buffers reuse the dead sT/xW region:
  float* y1 = ws;                    //  8,388,608  [256][128][16][16]
  float* y2 = ws + 8388608;          //  2,686,976  [256][164][8][8]
  float* y3 = ws + 11075584;         //    786,432  [256][192][4][4]
  float* y4 = ws + 11862016;         //    196,608  [256][192][2][2]
  float* y5 = ws + 12058624;         //     32,768  [256][128]
  // peak usage: 34,435,072 floats = 137.8 MB

  // h0 = c0 = 0 (must re-init every call; ws is poisoned once)
  zero_kernel<<<2000, 256, 0, stream>>>(hbuf, 512000);

  transpose_sent<<<512, 256, 0, stream>>>(sent1, sent2, sT);
  gemm_xw<<<dim3(256, 16), 256, 0, stream>>>(sT, Wih, bih, bhh, xW);

  for (int t = 0; t < 32; t++) {
    gemm_rec<<<dim3(16, 16), 256, 0, stream>>>(hbuf, Whh, xW, gbuf, t);
    lstm_gates<<<1000, 256, 0, stream>>>(gbuf, hbuf, cbuf, seq, t);
  }

  sim_kernel<<<256, 256, 0, stream>>>(seq, len1, len2, simm);
  greedy_kernel<<<256, 64, 0, stream>>>(simm, maskf);
  focus_kernel<<<12288, 256, 0, stream>>>(simm, maskf, len1, len2);

  conv_pool<12, 32, 16, 12><<<256, 256, 0, stream>>>(simm, c1w, c1b, y1, 128);
  conv_pool<128, 16, 16, 32><<<256, 256, 0, stream>>>(y1, c2w, c2b, y2, 164);
  conv_pool<164, 8, 12, 164><<<256, 256, 0, stream>>>(y2, c3w, c3b, y3, 192);
  conv_pool<192, 4, 3, 192><<<256, 256, 0, stream>>>(y3, c4w, c4b, y4, 192);
  conv_pool<192, 2, 1, 192><<<256, 256, 0, stream>>>(y4, c5w, c5b, y5, 128);

  dense_head<<<256, 128, 0, stream>>>(y5, dnn_w, dnn_b, out_w, out_b, out);
}

// Round 2
// 1248.200 us; speedup vs baseline: 1.9806x; 1.9806x over previous
//
#include <hip/hip_runtime.h>
#include <hip/hip_bf16.h>
#include <math.h>

// ---------------------------------------------------------------------------
// VDPWI forward. fp32 LSTM/sim/greedy (bit-safe argmax), bf16 MFMA convs.
// B=256, L=32, D=300, H=250, NLAB=5. NEG=-10000.
// ---------------------------------------------------------------------------

#define NEGV (-10000.0f)

typedef unsigned short u16;
typedef __attribute__((ext_vector_type(8))) short s8v;   // 8 bf16 (4 VGPR)
typedef __attribute__((ext_vector_type(4))) float f4v;

__device__ __forceinline__ float4 load4g(const float* __restrict__ p, int k, int K) {
  float4 r;
  if (k + 3 < K) {
    r = *(const float4*)(p + k);
  } else {
    r.x = (k     < K) ? p[k]     : 0.f;
    r.y = (k + 1 < K) ? p[k + 1] : 0.f;
    r.z = (k + 2 < K) ? p[k + 2] : 0.f;
    r.w = (k + 3 < K) ? p[k + 3] : 0.f;
  }
  return r;
}

// ---------------- zero init ----------------
__global__ __launch_bounds__(256) void zero_kernel(float* p, int n) {
  int i = blockIdx.x * 256 + threadIdx.x;
  if (i < n) p[i] = 0.f;
}
__global__ __launch_bounds__(256) void zero4_kernel(float4* p, int n4) {
  int i = blockIdx.x * 256 + threadIdx.x;
  if (i < n4) p[i] = make_float4(0.f, 0.f, 0.f, 0.f);
}

// ---------------- transpose sent [B,D,L] -> sT [2,B,L,D] ----------------
__global__ __launch_bounds__(256) void transpose_sent(const float* __restrict__ sent1,
                                                      const float* __restrict__ sent2,
                                                      float* __restrict__ sT) {
  int blk = blockIdx.x;            // s*256 + b
  int s = blk >> 8, b = blk & 255;
  const float* in = (s ? sent2 : sent1) + (size_t)b * 9600;   // [300][32]
  float* out = sT + (size_t)blk * 9600;                        // [32][300]
  __shared__ float lds[300 * 33];
  for (int idx = threadIdx.x; idx < 9600; idx += 256) {
    int d = idx >> 5, tt = idx & 31;
    lds[d * 33 + tt] = in[idx];
  }
  __syncthreads();
  for (int odx = threadIdx.x; odx < 9600; odx += 256) {
    int tt = odx / 300, d = odx % 300;
    out[odx] = lds[d * 33 + tt];
  }
}

// ---------------- xW GEMM (fp32) ----------------
__global__ __launch_bounds__(256) void gemm_xw(const float* __restrict__ sT,
                                               const float* __restrict__ Wih,
                                               const float* __restrict__ bih,
                                               const float* __restrict__ bhh,
                                               float* __restrict__ xW) {
  __shared__ float As[16][68];
  __shared__ float Bs[16][68];
  const int tid = threadIdx.x;
  const int i0 = blockIdx.x * 64;
  const int j0 = blockIdx.y * 64;
  const int tx = tid & 15, ty = tid >> 4;
  const int sm = tid >> 2, skq = (tid & 3) * 4;

  int i = i0 + sm;
  int s = i >> 13, r = i & 8191, t = r >> 8, bb = r & 255;
  const float* arow = sT + (size_t)(((s << 8) + bb) * 32 + t) * 300;
  int jrow = j0 + sm;
  bool jv = jrow < 1000;
  const float* wrow = Wih + (size_t)(jv ? jrow : 0) * 300;

  float acc[4][4];
#pragma unroll
  for (int a = 0; a < 4; a++)
#pragma unroll
    for (int c = 0; c < 4; c++) acc[a][c] = 0.f;

  for (int k0 = 0; k0 < 300; k0 += 16) {
    float4 av = load4g(arow, k0 + skq, 300);
    float4 wv;
    if (jv) wv = load4g(wrow, k0 + skq, 300);
    else { wv.x = wv.y = wv.z = wv.w = 0.f; }
    __syncthreads();
    As[skq + 0][sm] = av.x; As[skq + 1][sm] = av.y; As[skq + 2][sm] = av.z; As[skq + 3][sm] = av.w;
    Bs[skq + 0][sm] = wv.x; Bs[skq + 1][sm] = wv.y; Bs[skq + 2][sm] = wv.z; Bs[skq + 3][sm] = wv.w;
    __syncthreads();
#pragma unroll
    for (int k = 0; k < 16; k++) {
      float4 a = *(const float4*)&As[k][ty * 4];
      float4 bvec = *(const float4*)&Bs[k][tx * 4];
      acc[0][0] = fmaf(a.x, bvec.x, acc[0][0]); acc[0][1] = fmaf(a.x, bvec.y, acc[0][1]);
      acc[0][2] = fmaf(a.x, bvec.z, acc[0][2]); acc[0][3] = fmaf(a.x, bvec.w, acc[0][3]);
      acc[1][0] = fmaf(a.y, bvec.x, acc[1][0]); acc[1][1] = fmaf(a.y, bvec.y, acc[1][1]);
      acc[1][2] = fmaf(a.y, bvec.z, acc[1][2]); acc[1][3] = fmaf(a.y, bvec.w, acc[1][3]);
      acc[2][0] = fmaf(a.z, bvec.x, acc[2][0]); acc[2][1] = fmaf(a.z, bvec.y, acc[2][1]);
      acc[2][2] = fmaf(a.z, bvec.z, acc[2][2]); acc[2][3] = fmaf(a.z, bvec.w, acc[2][3]);
      acc[3][0] = fmaf(a.w, bvec.x, acc[3][0]); acc[3][1] = fmaf(a.w, bvec.y, acc[3][1]);
      acc[3][2] = fmaf(a.w, bvec.z, acc[3][2]); acc[3][3] = fmaf(a.w, bvec.w, acc[3][3]);
    }
  }
  int jb = j0 + tx * 4;
  if (jb < 1000) {
    float b0 = bih[jb]     + bhh[jb];
    float b1 = bih[jb + 1] + bhh[jb + 1];
    float b2 = bih[jb + 2] + bhh[jb + 2];
    float b3 = bih[jb + 3] + bhh[jb + 3];
#pragma unroll
    for (int rr = 0; rr < 4; rr++) {
      int irow = i0 + ty * 4 + rr;
      float4 o;
      o.x = acc[rr][0] + b0; o.y = acc[rr][1] + b1; o.z = acc[rr][2] + b2; o.w = acc[rr][3] + b3;
      *(float4*)(xW + (size_t)irow * 1000 + jb) = o;
    }
  }
}

// ---------------- recurrence GEMM (fp32) ----------------
__global__ __launch_bounds__(256) void gemm_rec(const float* __restrict__ hbuf,
                                                const float* __restrict__ Whh,
                                                const float* __restrict__ xW,
                                                float* __restrict__ gbuf, int t) {
  __shared__ float As[16][68];
  __shared__ float Bs[16][68];
  const int tid = threadIdx.x;
  const int i0 = blockIdx.x * 64;
  const int j0 = blockIdx.y * 64;
  const int tx = tid & 15, ty = tid >> 4;
  const int sm = tid >> 2, skq = (tid & 3) * 4;

  const float* arow = hbuf + (size_t)(i0 + sm) * 250;
  int jrow = j0 + sm;
  bool jv = jrow < 1000;
  const float* wrow = Whh + (size_t)(jv ? jrow : 0) * 250;

  float acc[4][4];
#pragma unroll
  for (int a = 0; a < 4; a++)
#pragma unroll
    for (int c = 0; c < 4; c++) acc[a][c] = 0.f;

  for (int k0 = 0; k0 < 250; k0 += 16) {
    float4 av = load4g(arow, k0 + skq, 250);
    float4 wv;
    if (jv) wv = load4g(wrow, k0 + skq, 250);
    else { wv.x = wv.y = wv.z = wv.w = 0.f; }
    __syncthreads();
    As[skq + 0][sm] = av.x; As[skq + 1][sm] = av.y; As[skq + 2][sm] = av.z; As[skq + 3][sm] = av.w;
    Bs[skq + 0][sm] = wv.x; Bs[skq + 1][sm] = wv.y; Bs[skq + 2][sm] = wv.z; Bs[skq + 3][sm] = wv.w;
    __syncthreads();
#pragma unroll
    for (int k = 0; k < 16; k++) {
      float4 a = *(const float4*)&As[k][ty * 4];
      float4 bvec = *(const float4*)&Bs[k][tx * 4];
      acc[0][0] = fmaf(a.x, bvec.x, acc[0][0]); acc[0][1] = fmaf(a.x, bvec.y, acc[0][1]);
      acc[0][2] = fmaf(a.x, bvec.z, acc[0][2]); acc[0][3] = fmaf(a.x, bvec.w, acc[0][3]);
      acc[1][0] = fmaf(a.y, bvec.x, acc[1][0]); acc[1][1] = fmaf(a.y, bvec.y, acc[1][1]);
      acc[1][2] = fmaf(a.y, bvec.z, acc[1][2]); acc[1][3] = fmaf(a.y, bvec.w, acc[1][3]);
      acc[2][0] = fmaf(a.z, bvec.x, acc[2][0]); acc[2][1] = fmaf(a.z, bvec.y, acc[2][1]);
      acc[2][2] = fmaf(a.z, bvec.z, acc[2][2]); acc[2][3] = fmaf(a.z, bvec.w, acc[2][3]);
      acc[3][0] = fmaf(a.w, bvec.x, acc[3][0]); acc[3][1] = fmaf(a.w, bvec.y, acc[3][1]);
      acc[3][2] = fmaf(a.w, bvec.z, acc[3][2]); acc[3][3] = fmaf(a.w, bvec.w, acc[3][3]);
    }
  }
  int jb = j0 + tx * 4;
  if (jb < 1000) {
#pragma unroll
    for (int rr = 0; rr < 4; rr++) {
      int irow = i0 + ty * 4 + rr;
      int l = irow >> 8, b = irow & 255;
      int s = l >> 1, dir = l & 1;
      int tin = dir ? (31 - t) : t;
      const float* xp = xW + (size_t)(((s * 32 + tin) << 8) + b) * 1000;
      float4 xv = *(const float4*)(xp + jb);
      float4 o;
      o.x = acc[rr][0] + xv.x; o.y = acc[rr][1] + xv.y;
      o.z = acc[rr][2] + xv.z; o.w = acc[rr][3] + xv.w;
      *(float4*)(gbuf + (size_t)irow * 1000 + jb) = o;
    }
  }
}

// ---------------- LSTM gates ----------------
__global__ __launch_bounds__(256) void lstm_gates(const float* __restrict__ gbuf,
                                                  float* __restrict__ hbuf,
                                                  float* __restrict__ cbuf,
                                                  float* __restrict__ seq, int t) {
  int idx = blockIdx.x * 256 + threadIdx.x;     // < 4*256*250
  int u = idx % 250;
  int ib = idx / 250;                            // l*256 + b
  const float* g = gbuf + (size_t)ib * 1000;
  float gi = g[u], gf = g[250 + u], gg = g[500 + u], go = g[750 + u];
  float c = cbuf[idx];
  float si = 1.f / (1.f + expf(-gi));
  float sf = 1.f / (1.f + expf(-gf));
  float so = 1.f / (1.f + expf(-go));
  float tg = tanhf(gg);
  float cn = sf * c + si * tg;
  float h = so * tanhf(cn);
  cbuf[idx] = cn;
  hbuf[idx] = h;
  seq[(size_t)(ib * 32 + t) * 250 + u] = h;
}

// ---------------- similarities: 12 channels + NEG padding ----------------
__global__ __launch_bounds__(256) void sim_kernel(const float* __restrict__ seq,
                                                  const int* __restrict__ len1,
                                                  const int* __restrict__ len2,
                                                  float* __restrict__ simm) {
  __shared__ float lds[4][32][65];
  const int b = blockIdx.x, tid = threadIdx.x;
  float dff[4], dbb[4], d9[4];
  float nf1[4], nb1[4], n91[4], nf2[4], nb2[4], n92[4];
#pragma unroll
  for (int pp = 0; pp < 4; pp++) {
    dff[pp] = dbb[pp] = d9[pp] = 0.f;
    nf1[pp] = nb1[pp] = n91[pp] = nf2[pp] = nb2[pp] = n92[pp] = 0.f;
  }
  for (int k0 = 0; k0 < 250; k0 += 64) {
    __syncthreads();
    for (int idx = tid; idx < 4 * 32 * 64; idx += 256) {
      int mat = idx >> 11, row = (idx >> 6) & 31, kk = idx & 63;
      int k = k0 + kk;
      lds[mat][row][kk] = (k < 250) ? seq[(size_t)((mat * 256 + b) * 32 + row) * 250 + k] : 0.f;
    }
    __syncthreads();
#pragma unroll
    for (int pp = 0; pp < 4; pp++) {
      int pr = tid + (pp << 8);
      int l = pr >> 5, m = pr & 31;
      for (int kk = 0; kk < 64; kk++) {
        float af = lds[0][l][kk], ab = lds[1][l][kk];
        float bf = lds[2][m][kk], bbv = lds[3][m][kk];
        float s1 = af + ab, s2 = bf + bbv;
        dff[pp] = fmaf(af, bf, dff[pp]);
        dbb[pp] = fmaf(ab, bbv, dbb[pp]);
        d9[pp]  = fmaf(s1, s2, d9[pp]);
        nf1[pp] = fmaf(af, af, nf1[pp]);
        nb1[pp] = fmaf(ab, ab, nb1[pp]);
        n91[pp] = fmaf(s1, s1, n91[pp]);
        nf2[pp] = fmaf(bf, bf, nf2[pp]);
        nb2[pp] = fmaf(bbv, bbv, nb2[pp]);
        n92[pp] = fmaf(s2, s2, n92[pp]);
      }
    }
  }
  int L1 = len1[b], L2 = len2[b];
  float* sb = simm + (size_t)b * 12 * 1024;
#pragma unroll
  for (int pp = 0; pp < 4; pp++) {
    int pr = tid + (pp << 8);
    int l = pr >> 5, m = pr & 31;
    float padv = (l >= L1 || m >= L2) ? NEGV : 0.f;
    float dcat = dff[pp] + dbb[pp];
    float n1c = nf1[pp] + nb1[pp], n2c = nf2[pp] + nb2[pp];
    sb[0 * 1024 + pr] = dcat + padv;
    sb[1 * 1024 + pr] = dcat / (sqrtf(n1c) * sqrtf(n2c) + 1e-8f) + padv;
    sb[2 * 1024 + pr] = sqrtf(fmaxf(n1c + n2c - 2.f * dcat, 1e-12f)) + padv;
    sb[3 * 1024 + pr] = dff[pp] + padv;
    sb[4 * 1024 + pr] = dff[pp] / (sqrtf(nf1[pp]) * sqrtf(nf2[pp]) + 1e-8f) + padv;
    sb[5 * 1024 + pr] = sqrtf(fmaxf(nf1[pp] + nf2[pp] - 2.f * dff[pp], 1e-12f)) + padv;
    sb[6 * 1024 + pr] = dbb[pp] + padv;
    sb[7 * 1024 + pr] = dbb[pp] / (sqrtf(nb1[pp]) * sqrtf(nb2[pp]) + 1e-8f) + padv;
    sb[8 * 1024 + pr] = sqrtf(fmaxf(nb1[pp] + nb2[pp] - 2.f * dbb[pp], 1e-12f)) + padv;
    sb[9 * 1024 + pr] = d9[pp] + padv;
    sb[10 * 1024 + pr] = d9[pp] / (sqrtf(n91[pp]) * sqrtf(n92[pp]) + 1e-8f) + padv;
    sb[11 * 1024 + pr] = sqrtf(fmaxf(n91[pp] + n92[pp] - 2.f * d9[pp], 1e-12f)) + padv;
  }
}

// ---------------- greedy NMS-style select -> mask (1.0/0.1) ----------------
__global__ __launch_bounds__(64) void greedy_kernel(const float* __restrict__ simm,
                                                    float* __restrict__ maskf) {
  const int b = blockIdx.x, lane = threadIdx.x;
  unsigned sel = 0;
#pragma unroll 1
  for (int ch = 0; ch < 2; ch++) {
    const float* mm = simm + (size_t)(b * 12 + 9 + ch) * 1024;
    float v[16];
#pragma unroll
    for (int q = 0; q < 16; q++) v[q] = mm[lane + (q << 6)];
#pragma unroll 1
    for (int it = 0; it < 32; it++) {
      float bv = v[0]; int bi = lane;
#pragma unroll
      for (int q = 1; q < 16; q++) {
        int idx = lane + (q << 6);
        if (v[q] > bv) { bv = v[q]; bi = idx; }
      }
#pragma unroll
      for (int off = 32; off > 0; off >>= 1) {
        float ov = __shfl_xor(bv, off);
        int oi = __shfl_xor(bi, off);
        if (ov > bv || (ov == bv && oi < bi)) { bv = ov; bi = oi; }
      }
      if (bv < -5000.0f) break;
      int rr = bi >> 5, cc = bi & 31;
#pragma unroll
      for (int q = 0; q < 16; q++) {
        int idx = lane + (q << 6);
        int ri = idx >> 5, ci = idx & 31;
        if (idx == bi) sel |= (1u << q);
        if (ri == rr || ci == cc) v[q] = NEGV;
      }
    }
  }
#pragma unroll
  for (int q = 0; q < 16; q++)
    maskf[(size_t)b * 1024 + lane + (q << 6)] = ((sel >> q) & 1u) ? 1.0f : 0.1f;
}

// ---------------- focus -> Xpad1 (bf16 NHWC, halo-padded, 32ch) ----------------
__global__ __launch_bounds__(256) void focus_write(const float* __restrict__ simm,
                                                   const float* __restrict__ maskf,
                                                   const int* __restrict__ len1,
                                                   const int* __restrict__ len2,
                                                   __hip_bfloat16* __restrict__ xp1) {
  const int b = blockIdx.x, tid = threadIdx.x;
  const int L1 = len1[b], L2 = len2[b];
  for (int px = tid; px < 1024; px += 256) {
    int y = px >> 5, x = px & 31;
    bool pad = (y >= L1) || (x >= L2);
    float mv = maskf[((size_t)b << 10) + px];
    __hip_bfloat16* o = xp1 + ((size_t)(b * 34 + 1 + y) * 34 + 1 + x) * 32;
#pragma unroll
    for (int ch = 0; ch < 12; ch++) {
      float v = pad ? 0.f : simm[(((size_t)b * 12 + ch) << 10) + px] * mv;
      o[ch] = __float2bfloat16(v);
    }
  }
}

// ---------------- weight transform: [COUT][CIN][3][3] f32 -> fragment-linear bf16
// k = (ky*3+kx)*CINP + ic ; frag(kg,ocg): elem(lane,j) = W[oc=ocg*16+(l&15)][k=kg*32+(l>>4)*8+j]
__global__ __launch_bounds__(256) void wtrans(const float* __restrict__ src,
                                              u16* __restrict__ dst,
                                              int CIN, int CINP, int COUT, int NOCG, int nelem) {
  int e = blockIdx.x * 256 + threadIdx.x;
  if (e >= nelem) return;
  int j = e & 7;
  int lane = (e >> 3) & 63;
  int fragidx = e >> 9;
  int ocg = fragidx % NOCG;
  int kg = fragidx / NOCG;
  int k = kg * 32 + (lane >> 4) * 8 + j;
  int kykx = k / CINP;
  int ic = k - kykx * CINP;
  int ky = kykx / 3, kx = kykx - ky * 3;
  int oc = ocg * 16 + (lane & 15);
  float v = 0.f;
  if (ic < CIN && oc < COUT)
    v = src[((size_t)(oc * CIN + ic) * 3 + ky) * 3 + kx];
  __hip_bfloat16 h = __float2bfloat16(v);
  dst[e] = *reinterpret_cast<u16*>(&h);
}

// ---------------- MFMA conv3x3(SAME)+bias+relu+pool2, implicit GEMM ----------
// in: [B][S+2][S+2][CINP] bf16 (halo zeros). wf: fragment-linear bf16.
// Block: MB=256 px (GI imgs x YR rows x S cols) x 64 oc. 4 waves split M.
// out: next Xpad [B][S/2+2][S/2+2][COUTP_NEXT] bf16 (or f32 [B][128] if LAST).
__device__ __forceinline__ int fsw(int u) { return (u ^ (u >> 2)) & 3; }

template<int S, int CINP, int GI, int TY, int COUTP_NEXT, bool LAST>
__global__ __launch_bounds__(256) void convk(const u16* __restrict__ in,
                                             const u16* __restrict__ wf,
                                             const float* __restrict__ bias,
                                             void* __restrict__ outv,
                                             int COUT, int NOCG) {
  constexpr int YR = S / TY;
  constexpr int SRX = S + 2, SRY = YR + 2;
  constexpr int PSTG = GI * SRY * SRX;
  constexpr int NCH = CINP / 32;
  constexpr int SN = S / 2;
  __shared__ u16 lds[PSTG * 32];

  const int tid = threadIdx.x;
  const int lane = tid & 63, w = tid >> 6;
  const int g = lane >> 4, li = lane & 15;
  const int bx = blockIdx.x;
  const int img0 = (bx / TY) * GI;
  const int ytile = bx - (bx / TY) * TY;
  const int ocbase = blockIdx.y * 64;

  // A addressing precompute (A-frag lane pixel: m = w*64 + f*16 + (lane&15))
  int pbase[4], xsv[4];
#pragma unroll
  for (int f = 0; f < 4; f++) {
    int m = w * 64 + f * 16 + li;
    int gi_ = m / (YR * S);
    int yl = (m / S) % YR;
    int xl = m % S;
    pbase[f] = gi_ * (SRY * SRX) + yl * SRX + xl;
    xsv[f] = xl;
  }

  f4v acc[4][4];
#pragma unroll
  for (int f = 0; f < 4; f++)
#pragma unroll
    for (int n = 0; n < 4; n++) acc[f][n] = (f4v){0.f, 0.f, 0.f, 0.f};

  for (int c0 = 0; c0 < NCH; c0++) {
    __syncthreads();
    // stage ic-chunk: linear LDS writes, swizzle applied on SOURCE chunk index
    const int P4 = PSTG * 4;
    for (int T = tid; T < P4; T += 256) {
      int p = T >> 2, s = T & 3;
      int gi_ = p / (SRY * SRX);
      int rem = p - gi_ * (SRY * SRX);
      int yp = rem / SRX;
      int xp = rem - yp * SRX;
      int gch = s ^ fsw(xp);
      size_t soff = ((size_t)((img0 + gi_) * (S + 2) + (ytile * YR + yp)) * (S + 2) + xp) * CINP
                    + c0 * 32 + gch * 8;
      uint4 v = *(const uint4*)(in + soff);
      *(uint4*)&lds[p * 32 + s * 8] = v;
    }
    __syncthreads();
#pragma unroll
    for (int kykx = 0; kykx < 9; kykx++) {
      const int ky = kykx / 3, kx = kykx - ky * 3;
      const int kg = kykx * NCH + c0;
      s8v bfr[4];
#pragma unroll
      for (int n = 0; n < 4; n++) {
        size_t boff = ((size_t)(kg * NOCG + (ocbase >> 4) + n) * 64 + lane) * 8;
        bfr[n] = *(const s8v*)(wf + boff);
      }
      s8v afr[4];
#pragma unroll
      for (int f = 0; f < 4; f++) {
        int p = pbase[f] + ky * SRX + kx;
        int slot = g ^ fsw(xsv[f] + kx);
        afr[f] = *(const s8v*)&lds[p * 32 + slot * 8];
      }
#pragma unroll
      for (int f = 0; f < 4; f++)
#pragma unroll
        for (int n = 0; n < 4; n++)
          acc[f][n] = __builtin_amdgcn_mfma_f32_16x16x32_bf16(afr[f], bfr[n], acc[f][n], 0, 0, 0);
    }
  }

  // ---- epilogue: fused pool + bias + relu + bf16 store ----
  float bia[4];
#pragma unroll
  for (int n = 0; n < 4; n++) {
    int oc = ocbase + n * 16 + li;
    bia[n] = (oc < COUT) ? bias[oc] : 0.f;
  }
  auto emit = [&](int b, int py, int px, int n, float v) {
    int oc = ocbase + n * 16 + li;
    if (oc < COUT) {
      float r = fmaxf(v + bia[n], 0.f);
      if constexpr (LAST) {
        ((float*)outv)[(size_t)b * 128 + oc] = r;
      } else {
        ((__hip_bfloat16*)outv)[((size_t)(b * (SN + 2) + 1 + py) * (SN + 2) + 1 + px) * COUTP_NEXT + oc]
            = __float2bfloat16(r);
      }
    }
  };
  // D lane pixel: m = w*64 + f*16 + g*4 + r
#pragma unroll
  for (int n = 0; n < 4; n++) {
    if constexpr (S == 32) {
#pragma unroll
      for (int p2 = 0; p2 < 2; p2++)
#pragma unroll
        for (int c = 0; c < 2; c++) {
          float v = fmaxf(fmaxf(acc[p2][n][2 * c], acc[p2][n][2 * c + 1]),
                          fmaxf(acc[p2 + 2][n][2 * c], acc[p2 + 2][n][2 * c + 1]));
          emit(img0, ytile * 4 + w, p2 * 8 + g * 2 + c, n, v);
        }
    } else if constexpr (S == 16) {
#pragma unroll
      for (int p2 = 0; p2 < 2; p2++)
#pragma unroll
        for (int c = 0; c < 2; c++) {
          float v = fmaxf(fmaxf(acc[2 * p2][n][2 * c], acc[2 * p2][n][2 * c + 1]),
                          fmaxf(acc[2 * p2 + 1][n][2 * c], acc[2 * p2 + 1][n][2 * c + 1]));
          emit(img0, w * 2 + p2, g * 2 + c, n, v);
        }
    } else if constexpr (S == 8) {
#pragma unroll
      for (int f = 0; f < 4; f++) {
        float h0 = fmaxf(acc[f][n][0], acc[f][n][1]);
        float h1 = fmaxf(acc[f][n][2], acc[f][n][3]);
        float v0 = fmaxf(h0, __shfl_xor(h0, 32));
        float v1 = fmaxf(h1, __shfl_xor(h1, 32));
        if (g < 2) {
          int px0 = (g & 1) * 2;
          emit(img0 + w, f, px0, n, v0);
          emit(img0 + w, f, px0 + 1, n, v1);
        }
      }
    } else if constexpr (S == 4) {
#pragma unroll
      for (int f = 0; f < 4; f++) {
        float h0 = fmaxf(acc[f][n][0], acc[f][n][1]);
        float h1 = fmaxf(acc[f][n][2], acc[f][n][3]);
        float v0 = fmaxf(h0, __shfl_xor(h0, 16));
        float v1 = fmaxf(h1, __shfl_xor(h1, 16));
        if (!(g & 1)) {
          emit(img0 + w * 4 + f, g >> 1, 0, n, v0);
          emit(img0 + w * 4 + f, g >> 1, 1, n, v1);
        }
      }
    } else {  // S == 2
#pragma unroll
      for (int f = 0; f < 4; f++) {
        float v = fmaxf(fmaxf(acc[f][n][0], acc[f][n][1]), fmaxf(acc[f][n][2], acc[f][n][3]));
        emit(img0 + w * 16 + f * 4 + g, 0, 0, n, v);
      }
    }
  }
}

// ---------------- dense head ----------------
__global__ __launch_bounds__(128) void dense_head(const float* __restrict__ y5,
                                                  const float* __restrict__ dnn_w,
                                                  const float* __restrict__ dnn_b,
                                                  const float* __restrict__ out_w,
                                                  const float* __restrict__ out_b,
                                                  float* __restrict__ out) {
  __shared__ float xs[128];
  __shared__ float hs[128];
  __shared__ float lg[8];
  int b = blockIdx.x, j = threadIdx.x;
  xs[j] = y5[(size_t)b * 128 + j];
  __syncthreads();
  float acc = dnn_b[j];
  for (int k = 0; k < 128; k++) acc = fmaf(xs[k], dnn_w[j * 128 + k], acc);
  hs[j] = fmaxf(acc, 0.f);
  __syncthreads();
  if (j < 5) {
    float l = out_b[j];
    for (int k = 0; k < 128; k++) l = fmaf(hs[k], out_w[j * 128 + k], l);
    lg[j] = l;
  }
  __syncthreads();
  if (j < 5) {
    float m = lg[0];
    for (int c = 1; c < 5; c++) m = fmaxf(m, lg[c]);
    float ssum = 0.f;
    for (int c = 0; c < 5; c++) ssum += expf(lg[c] - m);
    out[(size_t)b * 5 + j] = lg[j] - m - logf(ssum);
  }
}

// ---------------------------------------------------------------------------
extern "C" void kernel_launch(void* const* d_in, const int* in_sizes, int n_in,
                              void* d_out, int out_size, void* d_ws, size_t ws_size,
                              hipStream_t stream) {
  (void)in_sizes; (void)n_in; (void)out_size; (void)ws_size;
  const float* sent1 = (const float*)d_in[0];
  const float* sent2 = (const float*)d_in[1];
  const int*   len1  = (const int*)d_in[2];
  const int*   len2  = (const int*)d_in[3];
  const float* Wih   = (const float*)d_in[4];
  const float* Whh   = (const float*)d_in[5];
  const float* bih   = (const float*)d_in[6];
  const float* bhh   = (const float*)d_in[7];
  const float* c1w = (const float*)d_in[8];  const float* c1b = (const float*)d_in[9];
  const float* c2w = (const float*)d_in[10]; const float* c2b = (const float*)d_in[11];
  const float* c3w = (const float*)d_in[12]; const float* c3b = (const float*)d_in[13];
  const float* c4w = (const float*)d_in[14]; const float* c4b = (const float*)d_in[15];
  const float* c5w = (const float*)d_in[16]; const float* c5b = (const float*)d_in[17];
  const float* dnn_w = (const float*)d_in[18]; const float* dnn_b = (const float*)d_in[19];
  const float* out_w = (const float*)d_in[20]; const float* out_b = (const float*)d_in[21];
  float* out = (float*)d_out;
  float* ws = (float*)d_ws;

  // -------- workspace layout (float offsets) --------
  // live early:
  float* sT    = ws;                 //  4,915,200  [2][256][32][300]
  float* xW    = ws + 4915200;       // 16,384,000  [2][32][256][1000]
  float* seq   = ws + 21299200;      //  8,192,000  [4][256][32][250]
  float* hbuf  = ws + 29491200;      //    256,000
  float* cbuf  = ws + 29747200;      //    256,000
  float* gbuf  = ws + 30003200;      //  1,024,000
  float* simm  = ws + 31027200;      //  3,145,728  [256][12][32][32]
  float* maskf = ws + 34172928;      //    262,144
  // conv stage (after t-loop; reuses sT/xW region):
  __hip_bfloat16* xp1 = (__hip_bfloat16*)(ws);            // [256][34][34][32]
  __hip_bfloat16* xp2 = (__hip_bfloat16*)(ws + 4733952);  // [256][18][18][128]
  __hip_bfloat16* xp3 = (__hip_bfloat16*)(ws + 10042368); // [256][10][10][192]
  __hip_bfloat16* xp4 = (__hip_bfloat16*)(ws + 12499968); // [256][6][6][192]
  __hip_bfloat16* xp5 = (__hip_bfloat16*)(ws + 13384704); // [256][4][4][192] (end 13,777,920)
  // weight frags + y5 (after sim; reuses seq region):
  u16* w1f = (u16*)(ws + 21299200);  //  36,864 elems
  u16* w2f = (u16*)(ws + 21317632);  // 221,184
  u16* w3f = (u16*)(ws + 21428224);  // 331,776
  u16* w4f = (u16*)(ws + 21594112);  // 331,776
  u16* w5f = (u16*)(ws + 21760000);  // 221,184
  float* y5 = ws + 21870592;         //  32,768  [256][128]

  // h0 = c0 = 0
  zero_kernel<<<2000, 256, 0, stream>>>(hbuf, 512000);

  transpose_sent<<<512, 256, 0, stream>>>(sent1, sent2, sT);
  gemm_xw<<<dim3(256, 16), 256, 0, stream>>>(sT, Wih, bih, bhh, xW);

  for (int t = 0; t < 32; t++) {
    gemm_rec<<<dim3(16, 16), 256, 0, stream>>>(hbuf, Whh, xW, gbuf, t);
    lstm_gates<<<1000, 256, 0, stream>>>(gbuf, hbuf, cbuf, seq, t);
  }

  sim_kernel<<<256, 256, 0, stream>>>(seq, len1, len2, simm);
  greedy_kernel<<<256, 64, 0, stream>>>(simm, maskf);

  // zero all Xpad buffers (halo + padded channels), then fill interiors
  zero4_kernel<<<13455, 256, 0, stream>>>((float4*)ws, 3444480);

  // weight fragment transforms (seq region is dead now)
  wtrans<<<(36864 + 255) / 256, 256, 0, stream>>>(c1w, w1f, 12, 32, 128, 8, 36864);
  wtrans<<<(221184 + 255) / 256, 256, 0, stream>>>(c2w, w2f, 128, 128, 164, 12, 221184);
  wtrans<<<(331776 + 255) / 256, 256, 0, stream>>>(c3w, w3f, 164, 192, 192, 12, 331776);
  wtrans<<<(331776 + 255) / 256, 256, 0, stream>>>(c4w, w4f, 192, 192, 192, 12, 331776);
  wtrans<<<(221184 + 255) / 256, 256, 0, stream>>>(c5w, w5f, 192, 192, 128, 8, 221184);

  focus_write<<<256, 256, 0, stream>>>(simm, maskf, len1, len2, xp1);

  //            S   CINP GI  TY  CPN   LAST
  convk<32,  32,  1, 4, 128, false><<<dim3(1024, 2), 256, 0, stream>>>((const u16*)xp1, w1f, c1b, xp2, 128, 8);
  convk<16, 128,  1, 1, 192, false><<<dim3(256, 3), 256, 0, stream>>>((const u16*)xp2, w2f, c2b, xp3, 164, 12);
  convk< 8, 192,  4, 1, 192, false><<<dim3(64, 3), 256, 0, stream>>>((const u16*)xp3, w3f, c3b, xp4, 192, 12);
  convk< 4, 192, 16, 1, 192, false><<<dim3(16, 3), 256, 0, stream>>>((const u16*)xp4, w4f, c4b, xp5, 192, 12);
  convk< 2, 192, 64, 1,   0, true ><<<dim3(4, 2), 256, 0, stream>>>((const u16*)xp5, w5f, c5b, y5, 128, 8);

  dense_head<<<256, 128, 0, stream>>>(y5, dnn_w, dnn_b, out_w, out_b, out);
}

// Round 3
// 866.844 us; speedup vs baseline: 2.8519x; 1.4399x over previous
//
#include <hip/hip_runtime.h>
#include <hip/hip_bf16.h>
#include <math.h>

// ---------------------------------------------------------------------------
// VDPWI forward. fp32 LSTM (persistent, row-partitioned) / sim / greedy,
// bf16 MFMA convs. B=256, L=32, D=300, H=250, NLAB=5. NEG=-10000.
// ---------------------------------------------------------------------------

#define NEGV (-10000.0f)

typedef unsigned short u16;
typedef __attribute__((ext_vector_type(8))) short s8v;   // 8 bf16 (4 VGPR)
typedef __attribute__((ext_vector_type(4))) float f4v;

__device__ __forceinline__ float4 load4g(const float* __restrict__ p, int k, int K) {
  float4 r;
  if (k + 3 < K) {
    r = *(const float4*)(p + k);
  } else {
    r.x = (k     < K) ? p[k]     : 0.f;
    r.y = (k + 1 < K) ? p[k + 1] : 0.f;
    r.z = (k + 2 < K) ? p[k + 2] : 0.f;
    r.w = (k + 3 < K) ? p[k + 3] : 0.f;
  }
  return r;
}

// ---------------- zero init ----------------
__global__ __launch_bounds__(256) void zero4_kernel(float4* p, int n4) {
  int i = blockIdx.x * 256 + threadIdx.x;
  if (i < n4) p[i] = make_float4(0.f, 0.f, 0.f, 0.f);
}

// ---------------- transpose sent [B,D,L] -> sT [2,B,L,D] ----------------
__global__ __launch_bounds__(256) void transpose_sent(const float* __restrict__ sent1,
                                                      const float* __restrict__ sent2,
                                                      float* __restrict__ sT) {
  int blk = blockIdx.x;            // s*256 + b
  int s = blk >> 8, b = blk & 255;
  const float* in = (s ? sent2 : sent1) + (size_t)b * 9600;   // [300][32]
  float* out = sT + (size_t)blk * 9600;                        // [32][300]
  __shared__ float lds[300 * 33];
  for (int idx = threadIdx.x; idx < 9600; idx += 256) {
    int d = idx >> 5, tt = idx & 31;
    lds[d * 33 + tt] = in[idx];
  }
  __syncthreads();
  for (int odx = threadIdx.x; odx < 9600; odx += 256) {
    int tt = odx / 300, d = odx % 300;
    out[odx] = lds[d * 33 + tt];
  }
}

// ---------------- xW GEMM (fp32): xW[s,t,b,j] = sT·Wih^T + bih+bhh ----------
__global__ __launch_bounds__(256) void gemm_xw(const float* __restrict__ sT,
                                               const float* __restrict__ Wih,
                                               const float* __restrict__ bih,
                                               const float* __restrict__ bhh,
                                               float* __restrict__ xW) {
  __shared__ float As[16][68];
  __shared__ float Bs[16][68];
  const int tid = threadIdx.x;
  const int i0 = blockIdx.x * 64;
  const int j0 = blockIdx.y * 64;
  const int tx = tid & 15, ty = tid >> 4;
  const int sm = tid >> 2, skq = (tid & 3) * 4;

  int i = i0 + sm;
  int s = i >> 13, r = i & 8191, t = r >> 8, bb = r & 255;
  const float* arow = sT + (size_t)(((s << 8) + bb) * 32 + t) * 300;
  int jrow = j0 + sm;
  bool jv = jrow < 1000;
  const float* wrow = Wih + (size_t)(jv ? jrow : 0) * 300;

  float acc[4][4];
#pragma unroll
  for (int a = 0; a < 4; a++)
#pragma unroll
    for (int c = 0; c < 4; c++) acc[a][c] = 0.f;

  for (int k0 = 0; k0 < 300; k0 += 16) {
    float4 av = load4g(arow, k0 + skq, 300);
    float4 wv;
    if (jv) wv = load4g(wrow, k0 + skq, 300);
    else { wv.x = wv.y = wv.z = wv.w = 0.f; }
    __syncthreads();
    As[skq + 0][sm] = av.x; As[skq + 1][sm] = av.y; As[skq + 2][sm] = av.z; As[skq + 3][sm] = av.w;
    Bs[skq + 0][sm] = wv.x; Bs[skq + 1][sm] = wv.y; Bs[skq + 2][sm] = wv.z; Bs[skq + 3][sm] = wv.w;
    __syncthreads();
#pragma unroll
    for (int k = 0; k < 16; k++) {
      float4 a = *(const float4*)&As[k][ty * 4];
      float4 bvec = *(const float4*)&Bs[k][tx * 4];
      acc[0][0] = fmaf(a.x, bvec.x, acc[0][0]); acc[0][1] = fmaf(a.x, bvec.y, acc[0][1]);
      acc[0][2] = fmaf(a.x, bvec.z, acc[0][2]); acc[0][3] = fmaf(a.x, bvec.w, acc[0][3]);
      acc[1][0] = fmaf(a.y, bvec.x, acc[1][0]); acc[1][1] = fmaf(a.y, bvec.y, acc[1][1]);
      acc[1][2] = fmaf(a.y, bvec.z, acc[1][2]); acc[1][3] = fmaf(a.y, bvec.w, acc[1][3]);
      acc[2][0] = fmaf(a.z, bvec.x, acc[2][0]); acc[2][1] = fmaf(a.z, bvec.y, acc[2][1]);
      acc[2][2] = fmaf(a.z, bvec.z, acc[2][2]); acc[2][3] = fmaf(a.z, bvec.w, acc[2][3]);
      acc[3][0] = fmaf(a.w, bvec.x, acc[3][0]); acc[3][1] = fmaf(a.w, bvec.y, acc[3][1]);
      acc[3][2] = fmaf(a.w, bvec.z, acc[3][2]); acc[3][3] = fmaf(a.w, bvec.w, acc[3][3]);
    }
  }
  int jb = j0 + tx * 4;
  if (jb < 1000) {
    float b0 = bih[jb]     + bhh[jb];
    float b1 = bih[jb + 1] + bhh[jb + 1];
    float b2 = bih[jb + 2] + bhh[jb + 2];
    float b3 = bih[jb + 3] + bhh[jb + 3];
#pragma unroll
    for (int rr = 0; rr < 4; rr++) {
      int irow = i0 + ty * 4 + rr;
      float4 o;
      o.x = acc[rr][0] + b0; o.y = acc[rr][1] + b1; o.z = acc[rr][2] + b2; o.w = acc[rr][3] + b3;
      *(float4*)(xW + (size_t)irow * 1000 + jb) = o;
    }
  }
}

// ---------------- repack Whh[1000][250] -> Wg4[k][u] = {Wi,Wf,Wg,Wo}[u][k] ----
__global__ __launch_bounds__(256) void repack_whh(const float* __restrict__ Whh,
                                                  float4* __restrict__ Wg4) {
  int idx = blockIdx.x * 256 + threadIdx.x;   // k*250 + u
  if (idx >= 62500) return;
  int k = idx / 250, u = idx - k * 250;
  float4 v;
  v.x = Whh[(size_t)(u)       * 250 + k];
  v.y = Whh[(size_t)(250 + u) * 250 + k];
  v.z = Whh[(size_t)(500 + u) * 250 + k];
  v.w = Whh[(size_t)(750 + u) * 250 + k];
  Wg4[idx] = v;
}

// ---------------- persistent LSTM: all 32 steps, 4 rows per block ----------
// rows i = l*256+b (l: 0=s1f,1=s1b,2=s2f,3=s2b). Block bk owns i0=bk*4..+3
// (same l). h in LDS (hs[k] = rows 0..3 at dim k), c in VGPRs (thread u owns
// dim u of all 4 rows). No inter-block deps: row i of h(t) needs only row i
// of h(t-1). Wg streams from L2 (1MB, resident in every XCD L2).
__global__ __launch_bounds__(256) void lstm_persist(const float4* __restrict__ Wg4,
                                                    const float* __restrict__ xW,
                                                    float* __restrict__ seq) {
  __shared__ float4 hs[256];
  const int tid = threadIdx.x;
  const int i0 = blockIdx.x * 4;
  const int l = i0 >> 8;
  const int s = l >> 1, dir = l & 1;
  const int u = (tid < 250) ? tid : 249;
  const bool act = tid < 250;

  float4 c = make_float4(0.f, 0.f, 0.f, 0.f);
  hs[tid] = make_float4(0.f, 0.f, 0.f, 0.f);
  __syncthreads();

  const float4* wp = Wg4 + u;

  for (int t = 0; t < 32; t++) {
    const int tin = dir ? (31 - t) : t;
    const float* xb = xW + ((size_t)(s * 32 + tin) * 256 + (i0 & 255)) * 1000 + u;
    // prefetch gate inputs (independent of hs; hides HBM latency under k-loop)
    float xv[16];
#pragma unroll
    for (int r = 0; r < 4; r++)
#pragma unroll
      for (int q = 0; q < 4; q++)
        xv[r * 4 + q] = xb[r * 1000 + q * 250];

    float4 a0 = {0.f,0.f,0.f,0.f}, a1 = a0, a2 = a0, a3 = a0;
#pragma unroll 10
    for (int k = 0; k < 250; k++) {
      float4 w = wp[(size_t)k * 250];
      float4 h = hs[k];
      a0.x = fmaf(h.x, w.x, a0.x); a0.y = fmaf(h.x, w.y, a0.y);
      a0.z = fmaf(h.x, w.z, a0.z); a0.w = fmaf(h.x, w.w, a0.w);
      a1.x = fmaf(h.y, w.x, a1.x); a1.y = fmaf(h.y, w.y, a1.y);
      a1.z = fmaf(h.y, w.z, a1.z); a1.w = fmaf(h.y, w.w, a1.w);
      a2.x = fmaf(h.z, w.x, a2.x); a2.y = fmaf(h.z, w.y, a2.y);
      a2.z = fmaf(h.z, w.z, a2.z); a2.w = fmaf(h.z, w.w, a2.w);
      a3.x = fmaf(h.w, w.x, a3.x); a3.y = fmaf(h.w, w.y, a3.y);
      a3.z = fmaf(h.w, w.z, a3.z); a3.w = fmaf(h.w, w.w, a3.w);
    }
    __syncthreads();   // all hs reads done before overwrite
    if (act) {
      float4 hnew;
      {
        float gi = a0.x + xv[0],  gf = a0.y + xv[1],  gg = a0.z + xv[2],  go = a0.w + xv[3];
        float si = 1.f / (1.f + expf(-gi)), sf = 1.f / (1.f + expf(-gf)), so = 1.f / (1.f + expf(-go));
        c.x = sf * c.x + si * tanhf(gg);
        hnew.x = so * tanhf(c.x);
      }
      {
        float gi = a1.x + xv[4],  gf = a1.y + xv[5],  gg = a1.z + xv[6],  go = a1.w + xv[7];
        float si = 1.f / (1.f + expf(-gi)), sf = 1.f / (1.f + expf(-gf)), so = 1.f / (1.f + expf(-go));
        c.y = sf * c.y + si * tanhf(gg);
        hnew.y = so * tanhf(c.y);
      }
      {
        float gi = a2.x + xv[8],  gf = a2.y + xv[9],  gg = a2.z + xv[10], go = a2.w + xv[11];
        float si = 1.f / (1.f + expf(-gi)), sf = 1.f / (1.f + expf(-gf)), so = 1.f / (1.f + expf(-go));
        c.z = sf * c.z + si * tanhf(gg);
        hnew.z = so * tanhf(c.z);
      }
      {
        float gi = a3.x + xv[12], gf = a3.y + xv[13], gg = a3.z + xv[14], go = a3.w + xv[15];
        float si = 1.f / (1.f + expf(-gi)), sf = 1.f / (1.f + expf(-gf)), so = 1.f / (1.f + expf(-go));
        c.w = sf * c.w + si * tanhf(gg);
        hnew.w = so * tanhf(c.w);
      }
      hs[u] = hnew;
      size_t sb = ((size_t)i0 * 32 + t) * 250 + u;   // row stride 32*250=8000
      seq[sb]          = hnew.x;
      seq[sb + 8000]   = hnew.y;
      seq[sb + 16000]  = hnew.z;
      seq[sb + 24000]  = hnew.w;
    }
    __syncthreads();   // writes visible before next step's reads
  }
}

// ---------------- similarities: 12 channels + NEG padding ----------------
__global__ __launch_bounds__(256) void sim_kernel(const float* __restrict__ seq,
                                                  const int* __restrict__ len1,
                                                  const int* __restrict__ len2,
                                                  float* __restrict__ simm) {
  __shared__ float lds[4][32][65];
  const int b = blockIdx.x, tid = threadIdx.x;
  float dff[4], dbb[4], d9[4];
  float nf1[4], nb1[4], n91[4], nf2[4], nb2[4], n92[4];
#pragma unroll
  for (int pp = 0; pp < 4; pp++) {
    dff[pp] = dbb[pp] = d9[pp] = 0.f;
    nf1[pp] = nb1[pp] = n91[pp] = nf2[pp] = nb2[pp] = n92[pp] = 0.f;
  }
  for (int k0 = 0; k0 < 250; k0 += 64) {
    __syncthreads();
    for (int idx = tid; idx < 4 * 32 * 64; idx += 256) {
      int mat = idx >> 11, row = (idx >> 6) & 31, kk = idx & 63;
      int k = k0 + kk;
      lds[mat][row][kk] = (k < 250) ? seq[(size_t)((mat * 256 + b) * 32 + row) * 250 + k] : 0.f;
    }
    __syncthreads();
#pragma unroll
    for (int pp = 0; pp < 4; pp++) {
      int pr = tid + (pp << 8);
      int l = pr >> 5, m = pr & 31;
      for (int kk = 0; kk < 64; kk++) {
        float af = lds[0][l][kk], ab = lds[1][l][kk];
        float bf = lds[2][m][kk], bbv = lds[3][m][kk];
        float s1 = af + ab, s2 = bf + bbv;
        dff[pp] = fmaf(af, bf, dff[pp]);
        dbb[pp] = fmaf(ab, bbv, dbb[pp]);
        d9[pp]  = fmaf(s1, s2, d9[pp]);
        nf1[pp] = fmaf(af, af, nf1[pp]);
        nb1[pp] = fmaf(ab, ab, nb1[pp]);
        n91[pp] = fmaf(s1, s1, n91[pp]);
        nf2[pp] = fmaf(bf, bf, nf2[pp]);
        nb2[pp] = fmaf(bbv, bbv, nb2[pp]);
        n92[pp] = fmaf(s2, s2, n92[pp]);
      }
    }
  }
  int L1 = len1[b], L2 = len2[b];
  float* sb = simm + (size_t)b * 12 * 1024;
#pragma unroll
  for (int pp = 0; pp < 4; pp++) {
    int pr = tid + (pp << 8);
    int l = pr >> 5, m = pr & 31;
    float padv = (l >= L1 || m >= L2) ? NEGV : 0.f;
    float dcat = dff[pp] + dbb[pp];
    float n1c = nf1[pp] + nb1[pp], n2c = nf2[pp] + nb2[pp];
    sb[0 * 1024 + pr] = dcat + padv;
    sb[1 * 1024 + pr] = dcat / (sqrtf(n1c) * sqrtf(n2c) + 1e-8f) + padv;
    sb[2 * 1024 + pr] = sqrtf(fmaxf(n1c + n2c - 2.f * dcat, 1e-12f)) + padv;
    sb[3 * 1024 + pr] = dff[pp] + padv;
    sb[4 * 1024 + pr] = dff[pp] / (sqrtf(nf1[pp]) * sqrtf(nf2[pp]) + 1e-8f) + padv;
    sb[5 * 1024 + pr] = sqrtf(fmaxf(nf1[pp] + nf2[pp] - 2.f * dff[pp], 1e-12f)) + padv;
    sb[6 * 1024 + pr] = dbb[pp] + padv;
    sb[7 * 1024 + pr] = dbb[pp] / (sqrtf(nb1[pp]) * sqrtf(nb2[pp]) + 1e-8f) + padv;
    sb[8 * 1024 + pr] = sqrtf(fmaxf(nb1[pp] + nb2[pp] - 2.f * dbb[pp], 1e-12f)) + padv;
    sb[9 * 1024 + pr] = d9[pp] + padv;
    sb[10 * 1024 + pr] = d9[pp] / (sqrtf(n91[pp]) * sqrtf(n92[pp]) + 1e-8f) + padv;
    sb[11 * 1024 + pr] = sqrtf(fmaxf(n91[pp] + n92[pp] - 2.f * d9[pp], 1e-12f)) + padv;
  }
}

// ---------------- greedy NMS-style select -> mask (1.0/0.1) ----------------
__global__ __launch_bounds__(64) void greedy_kernel(const float* __restrict__ simm,
                                                    float* __restrict__ maskf) {
  const int b = blockIdx.x, lane = threadIdx.x;
  unsigned sel = 0;
#pragma unroll 1
  for (int ch = 0; ch < 2; ch++) {
    const float* mm = simm + (size_t)(b * 12 + 9 + ch) * 1024;
    float v[16];
#pragma unroll
    for (int q = 0; q < 16; q++) v[q] = mm[lane + (q << 6)];
#pragma unroll 1
    for (int it = 0; it < 32; it++) {
      float bv = v[0]; int bi = lane;
#pragma unroll
      for (int q = 1; q < 16; q++) {
        int idx = lane + (q << 6);
        if (v[q] > bv) { bv = v[q]; bi = idx; }
      }
#pragma unroll
      for (int off = 32; off > 0; off >>= 1) {
        float ov = __shfl_xor(bv, off);
        int oi = __shfl_xor(bi, off);
        if (ov > bv || (ov == bv && oi < bi)) { bv = ov; bi = oi; }
      }
      if (bv < -5000.0f) break;
      int rr = bi >> 5, cc = bi & 31;
#pragma unroll
      for (int q = 0; q < 16; q++) {
        int idx = lane + (q << 6);
        int ri = idx >> 5, ci = idx & 31;
        if (idx == bi) sel |= (1u << q);
        if (ri == rr || ci == cc) v[q] = NEGV;
      }
    }
  }
#pragma unroll
  for (int q = 0; q < 16; q++)
    maskf[(size_t)b * 1024 + lane + (q << 6)] = ((sel >> q) & 1u) ? 1.0f : 0.1f;
}

// ---------------- focus -> Xpad1 (bf16 NHWC, halo-padded, 32ch) ----------------
__global__ __launch_bounds__(256) void focus_write(const float* __restrict__ simm,
                                                   const float* __restrict__ maskf,
                                                   const int* __restrict__ len1,
                                                   const int* __restrict__ len2,
                                                   __hip_bfloat16* __restrict__ xp1) {
  const int b = blockIdx.x, tid = threadIdx.x;
  const int L1 = len1[b], L2 = len2[b];
  for (int px = tid; px < 1024; px += 256) {
    int y = px >> 5, x = px & 31;
    bool pad = (y >= L1) || (x >= L2);
    float mv = maskf[((size_t)b << 10) + px];
    __hip_bfloat16* o = xp1 + ((size_t)(b * 34 + 1 + y) * 34 + 1 + x) * 32;
#pragma unroll
    for (int ch = 0; ch < 12; ch++) {
      float v = pad ? 0.f : simm[(((size_t)b * 12 + ch) << 10) + px] * mv;
      o[ch] = __float2bfloat16(v);
    }
  }
}

// ---------------- weight transform: [COUT][CIN][3][3] f32 -> fragment-linear bf16
__global__ __launch_bounds__(256) void wtrans(const float* __restrict__ src,
                                              u16* __restrict__ dst,
                                              int CIN, int CINP, int COUT, int NOCG, int nelem) {
  int e = blockIdx.x * 256 + threadIdx.x;
  if (e >= nelem) return;
  int j = e & 7;
  int lane = (e >> 3) & 63;
  int fragidx = e >> 9;
  int ocg = fragidx % NOCG;
  int kg = fragidx / NOCG;
  int k = kg * 32 + (lane >> 4) * 8 + j;
  int kykx = k / CINP;
  int ic = k - kykx * CINP;
  int ky = kykx / 3, kx = kykx - ky * 3;
  int oc = ocg * 16 + (lane & 15);
  float v = 0.f;
  if (ic < CIN && oc < COUT)
    v = src[((size_t)(oc * CIN + ic) * 3 + ky) * 3 + kx];
  __hip_bfloat16 h = __float2bfloat16(v);
  dst[e] = *reinterpret_cast<u16*>(&h);
}

// ---------------- MFMA conv3x3(SAME)+bias+relu+pool2, implicit GEMM ----------
__device__ __forceinline__ int fsw(int u) { return (u ^ (u >> 2)) & 3; }

template<int S, int CINP, int GI, int TY, int COUTP_NEXT, bool LAST>
__global__ __launch_bounds__(256) void convk(const u16* __restrict__ in,
                                             const u16* __restrict__ wf,
                                             const float* __restrict__ bias,
                                             void* __restrict__ outv,
                                             int COUT, int NOCG) {
  constexpr int YR = S / TY;
  constexpr int SRX = S + 2, SRY = YR + 2;
  constexpr int PSTG = GI * SRY * SRX;
  constexpr int NCH = CINP / 32;
  constexpr int SN = S / 2;
  __shared__ u16 lds[PSTG * 32];

  const int tid = threadIdx.x;
  const int lane = tid & 63, w = tid >> 6;
  const int g = lane >> 4, li = lane & 15;
  const int bx = blockIdx.x;
  const int img0 = (bx / TY) * GI;
  const int ytile = bx - (bx / TY) * TY;
  const int ocbase = blockIdx.y * 64;

  int pbase[4], xsv[4];
#pragma unroll
  for (int f = 0; f < 4; f++) {
    int m = w * 64 + f * 16 + li;
    int gi_ = m / (YR * S);
    int yl = (m / S) % YR;
    int xl = m % S;
    pbase[f] = gi_ * (SRY * SRX) + yl * SRX + xl;
    xsv[f] = xl;
  }

  f4v acc[4][4];
#pragma unroll
  for (int f = 0; f < 4; f++)
#pragma unroll
    for (int n = 0; n < 4; n++) acc[f][n] = (f4v){0.f, 0.f, 0.f, 0.f};

  for (int c0 = 0; c0 < NCH; c0++) {
    __syncthreads();
    const int P4 = PSTG * 4;
    for (int T = tid; T < P4; T += 256) {
      int p = T >> 2, s = T & 3;
      int gi_ = p / (SRY * SRX);
      int rem = p - gi_ * (SRY * SRX);
      int yp = rem / SRX;
      int xp = rem - yp * SRX;
      int gch = s ^ fsw(xp);
      size_t soff = ((size_t)((img0 + gi_) * (S + 2) + (ytile * YR + yp)) * (S + 2) + xp) * CINP
                    + c0 * 32 + gch * 8;
      uint4 v = *(const uint4*)(in + soff);
      *(uint4*)&lds[p * 32 + s * 8] = v;
    }
    __syncthreads();
#pragma unroll
    for (int kykx = 0; kykx < 9; kykx++) {
      const int ky = kykx / 3, kx = kykx - ky * 3;
      const int kg = kykx * NCH + c0;
      s8v bfr[4];
#pragma unroll
      for (int n = 0; n < 4; n++) {
        size_t boff = ((size_t)(kg * NOCG + (ocbase >> 4) + n) * 64 + lane) * 8;
        bfr[n] = *(const s8v*)(wf + boff);
      }
      s8v afr[4];
#pragma unroll
      for (int f = 0; f < 4; f++) {
        int p = pbase[f] + ky * SRX + kx;
        int slot = g ^ fsw(xsv[f] + kx);
        afr[f] = *(const s8v*)&lds[p * 32 + slot * 8];
      }
#pragma unroll
      for (int f = 0; f < 4; f++)
#pragma unroll
        for (int n = 0; n < 4; n++)
          acc[f][n] = __builtin_amdgcn_mfma_f32_16x16x32_bf16(afr[f], bfr[n], acc[f][n], 0, 0, 0);
    }
  }

  float bia[4];
#pragma unroll
  for (int n = 0; n < 4; n++) {
    int oc = ocbase + n * 16 + li;
    bia[n] = (oc < COUT) ? bias[oc] : 0.f;
  }
  auto emit = [&](int b, int py, int px, int n, float v) {
    int oc = ocbase + n * 16 + li;
    if (oc < COUT) {
      float r = fmaxf(v + bia[n], 0.f);
      if constexpr (LAST) {
        ((float*)outv)[(size_t)b * 128 + oc] = r;
      } else {
        ((__hip_bfloat16*)outv)[((size_t)(b * (SN + 2) + 1 + py) * (SN + 2) + 1 + px) * COUTP_NEXT + oc]
            = __float2bfloat16(r);
      }
    }
  };
#pragma unroll
  for (int n = 0; n < 4; n++) {
    if constexpr (S == 32) {
#pragma unroll
      for (int p2 = 0; p2 < 2; p2++)
#pragma unroll
        for (int c = 0; c < 2; c++) {
          float v = fmaxf(fmaxf(acc[p2][n][2 * c], acc[p2][n][2 * c + 1]),
                          fmaxf(acc[p2 + 2][n][2 * c], acc[p2 + 2][n][2 * c + 1]));
          emit(img0, ytile * 4 + w, p2 * 8 + g * 2 + c, n, v);
        }
    } else if constexpr (S == 16) {
#pragma unroll
      for (int p2 = 0; p2 < 2; p2++)
#pragma unroll
        for (int c = 0; c < 2; c++) {
          float v = fmaxf(fmaxf(acc[2 * p2][n][2 * c], acc[2 * p2][n][2 * c + 1]),
                          fmaxf(acc[2 * p2 + 1][n][2 * c], acc[2 * p2 + 1][n][2 * c + 1]));
          emit(img0, w * 2 + p2, g * 2 + c, n, v);
        }
    } else if constexpr (S == 8) {
#pragma unroll
      for (int f = 0; f < 4; f++) {
        float h0 = fmaxf(acc[f][n][0], acc[f][n][1]);
        float h1 = fmaxf(acc[f][n][2], acc[f][n][3]);
        float v0 = fmaxf(h0, __shfl_xor(h0, 32));
        float v1 = fmaxf(h1, __shfl_xor(h1, 32));
        if (g < 2) {
          int px0 = (g & 1) * 2;
          emit(img0 + w, f, px0, n, v0);
          emit(img0 + w, f, px0 + 1, n, v1);
        }
      }
    } else if constexpr (S == 4) {
#pragma unroll
      for (int f = 0; f < 4; f++) {
        float h0 = fmaxf(acc[f][n][0], acc[f][n][1]);
        float h1 = fmaxf(acc[f][n][2], acc[f][n][3]);
        float v0 = fmaxf(h0, __shfl_xor(h0, 16));
        float v1 = fmaxf(h1, __shfl_xor(h1, 16));
        if (!(g & 1)) {
          emit(img0 + w * 4 + f, g >> 1, 0, n, v0);
          emit(img0 + w * 4 + f, g >> 1, 1, n, v1);
        }
      }
    } else {  // S == 2
#pragma unroll
      for (int f = 0; f < 4; f++) {
        float v = fmaxf(fmaxf(acc[f][n][0], acc[f][n][1]), fmaxf(acc[f][n][2], acc[f][n][3]));
        emit(img0 + w * 16 + f * 4 + g, 0, 0, n, v);
      }
    }
  }
}

// ---------------- dense head ----------------
__global__ __launch_bounds__(128) void dense_head(const float* __restrict__ y5,
                                                  const float* __restrict__ dnn_w,
                                                  const float* __restrict__ dnn_b,
                                                  const float* __restrict__ out_w,
                                                  const float* __restrict__ out_b,
                                                  float* __restrict__ out) {
  __shared__ float xs[128];
  __shared__ float hs[128];
  __shared__ float lg[8];
  int b = blockIdx.x, j = threadIdx.x;
  xs[j] = y5[(size_t)b * 128 + j];
  __syncthreads();
  float acc = dnn_b[j];
  for (int k = 0; k < 128; k++) acc = fmaf(xs[k], dnn_w[j * 128 + k], acc);
  hs[j] = fmaxf(acc, 0.f);
  __syncthreads();
  if (j < 5) {
    float l = out_b[j];
    for (int k = 0; k < 128; k++) l = fmaf(hs[k], out_w[j * 128 + k], l);
    lg[j] = l;
  }
  __syncthreads();
  if (j < 5) {
    float m = lg[0];
    for (int c = 1; c < 5; c++) m = fmaxf(m, lg[c]);
    float ssum = 0.f;
    for (int c = 0; c < 5; c++) ssum += expf(lg[c] - m);
    out[(size_t)b * 5 + j] = lg[j] - m - logf(ssum);
  }
}

// ---------------------------------------------------------------------------
extern "C" void kernel_launch(void* const* d_in, const int* in_sizes, int n_in,
                              void* d_out, int out_size, void* d_ws, size_t ws_size,
                              hipStream_t stream) {
  (void)in_sizes; (void)n_in; (void)out_size; (void)ws_size;
  const float* sent1 = (const float*)d_in[0];
  const float* sent2 = (const float*)d_in[1];
  const int*   len1  = (const int*)d_in[2];
  const int*   len2  = (const int*)d_in[3];
  const float* Wih   = (const float*)d_in[4];
  const float* Whh   = (const float*)d_in[5];
  const float* bih   = (const float*)d_in[6];
  const float* bhh   = (const float*)d_in[7];
  const float* c1w = (const float*)d_in[8];  const float* c1b = (const float*)d_in[9];
  const float* c2w = (const float*)d_in[10]; const float* c2b = (const float*)d_in[11];
  const float* c3w = (const float*)d_in[12]; const float* c3b = (const float*)d_in[13];
  const float* c4w = (const float*)d_in[14]; const float* c4b = (const float*)d_in[15];
  const float* c5w = (const float*)d_in[16]; const float* c5b = (const float*)d_in[17];
  const float* dnn_w = (const float*)d_in[18]; const float* dnn_b = (const float*)d_in[19];
  const float* out_w = (const float*)d_in[20]; const float* out_b = (const float*)d_in[21];
  float* out = (float*)d_out;
  float* ws = (float*)d_ws;

  // -------- workspace layout (float offsets) --------
  float* sT    = ws;                 //  4,915,200  [2][256][32][300]
  float* xW    = ws + 4915200;       // 16,384,000  [2][32][256][1000]
  float* seq   = ws + 21299200;      //  8,192,000  [4][256][32][250]
  float4* Wg4  = (float4*)(ws + 29491200); // 62,500 float4 = 250,000 floats
  float* simm  = ws + 31027200;      //  3,145,728  [256][12][32][32]
  float* maskf = ws + 34172928;      //    262,144
  // conv stage (reuses sT/xW region):
  __hip_bfloat16* xp1 = (__hip_bfloat16*)(ws);            // [256][34][34][32]
  __hip_bfloat16* xp2 = (__hip_bfloat16*)(ws + 4733952);  // [256][18][18][128]
  __hip_bfloat16* xp3 = (__hip_bfloat16*)(ws + 10042368); // [256][10][10][192]
  __hip_bfloat16* xp4 = (__hip_bfloat16*)(ws + 12499968); // [256][6][6][192]
  __hip_bfloat16* xp5 = (__hip_bfloat16*)(ws + 13384704); // [256][4][4][192]
  // weight frags + y5 (reuses seq region after sim_kernel):
  u16* w1f = (u16*)(ws + 21299200);
  u16* w2f = (u16*)(ws + 21317632);
  u16* w3f = (u16*)(ws + 21428224);
  u16* w4f = (u16*)(ws + 21594112);
  u16* w5f = (u16*)(ws + 21760000);
  float* y5 = ws + 21870592;

  transpose_sent<<<512, 256, 0, stream>>>(sent1, sent2, sT);
  gemm_xw<<<dim3(256, 16), 256, 0, stream>>>(sT, Wih, bih, bhh, xW);
  repack_whh<<<245, 256, 0, stream>>>(Whh, Wg4);

  lstm_persist<<<256, 256, 0, stream>>>(Wg4, xW, seq);

  sim_kernel<<<256, 256, 0, stream>>>(seq, len1, len2, simm);
  greedy_kernel<<<256, 64, 0, stream>>>(simm, maskf);

  // zero all Xpad buffers (halo + padded channels), then fill interiors
  zero4_kernel<<<13455, 256, 0, stream>>>((float4*)ws, 3444480);

  wtrans<<<(36864 + 255) / 256, 256, 0, stream>>>(c1w, w1f, 12, 32, 128, 8, 36864);
  wtrans<<<(221184 + 255) / 256, 256, 0, stream>>>(c2w, w2f, 128, 128, 164, 12, 221184);
  wtrans<<<(331776 + 255) / 256, 256, 0, stream>>>(c3w, w3f, 164, 192, 192, 12, 331776);
  wtrans<<<(331776 + 255) / 256, 256, 0, stream>>>(c4w, w4f, 192, 192, 192, 12, 331776);
  wtrans<<<(221184 + 255) / 256, 256, 0, stream>>>(c5w, w5f, 192, 192, 128, 8, 221184);

  focus_write<<<256, 256, 0, stream>>>(simm, maskf, len1, len2, xp1);

  //            S   CINP GI  TY  CPN   LAST
  convk<32,  32,  1, 4, 128, false><<<dim3(1024, 2), 256, 0, stream>>>((const u16*)xp1, w1f, c1b, xp2, 128, 8);
  convk<16, 128,  1, 1, 192, false><<<dim3(256, 3), 256, 0, stream>>>((const u16*)xp2, w2f, c2b, xp3, 164, 12);
  convk< 8, 192,  4, 1, 192, false><<<dim3(64, 3), 256, 0, stream>>>((const u16*)xp3, w3f, c3b, xp4, 192, 12);
  convk< 4, 192, 16, 1, 192, false><<<dim3(16, 3), 256, 0, stream>>>((const u16*)xp4, w4f, c4b, xp5, 192, 12);
  convk< 2, 192, 64, 1,   0, true ><<<dim3(4, 2), 256, 0, stream>>>((const u16*)xp5, w5f, c5b, y5, 128, 8);

  dense_head<<<256, 128, 0, stream>>>(y5, dnn_w, dnn_b, out_w, out_b, out);
}